// Round 1
// baseline (2890.408 us; speedup 1.0000x reference)
//
#include <hip/hip_runtime.h>

#define NN 50000
#define NE 800000
#define CIN 128
#define HH 64
#define NCLS 40
#define NL 15
#define DTC 0.1f
#define LNEPS 1e-5f
#define NB_SCAN 196   // ceil(50000/256)

// ---------------- degree / normalization precompute ----------------

__global__ __launch_bounds__(256) void k_deg(const int* __restrict__ dst, int* __restrict__ deg) {
    int e = blockIdx.x * 256 + threadIdx.x;
    if (e < NE) atomicAdd(&deg[dst[e]], 1);
}

__global__ __launch_bounds__(256) void k_dinv(const int* __restrict__ deg, float* __restrict__ dinv) {
    int n = blockIdx.x * 256 + threadIdx.x;
    if (n < NN) dinv[n] = rsqrtf(fmaxf((float)deg[n], 1.0f));
}

// exclusive scan of deg -> row_ptr (3 kernels)
__global__ __launch_bounds__(256) void k_scan1(const int* __restrict__ deg, int* __restrict__ rp,
                                               int* __restrict__ bsum) {
    int i = blockIdx.x * 256 + threadIdx.x;
    int v = (i < NN) ? deg[i] : 0;
    int lane = threadIdx.x & 63, wid = threadIdx.x >> 6;
    int inc = v;
#pragma unroll
    for (int d = 1; d < 64; d <<= 1) {
        int t = __shfl_up(inc, d, 64);
        if (lane >= d) inc += t;
    }
    __shared__ int wsum[4];
    if (lane == 63) wsum[wid] = inc;
    __syncthreads();
    int woff = 0;
#pragma unroll
    for (int w = 0; w < 4; ++w)
        if (w < wid) woff += wsum[w];
    if (i < NN) rp[i] = woff + inc - v;   // exclusive within block
    if (threadIdx.x == 255) bsum[blockIdx.x] = woff + inc;
}

__global__ __launch_bounds__(256) void k_scan2(const int* __restrict__ bsum, int* __restrict__ boff) {
    int t = threadIdx.x;
    int v = (t < NB_SCAN) ? bsum[t] : 0;
    int lane = t & 63, wid = t >> 6;
    int inc = v;
#pragma unroll
    for (int d = 1; d < 64; d <<= 1) {
        int tt = __shfl_up(inc, d, 64);
        if (lane >= d) inc += tt;
    }
    __shared__ int wsum[4];
    if (lane == 63) wsum[wid] = inc;
    __syncthreads();
    int woff = 0;
#pragma unroll
    for (int w = 0; w < 4; ++w)
        if (w < wid) woff += wsum[w];
    boff[t] = woff + inc - v;             // exclusive across blocks
}

__global__ __launch_bounds__(256) void k_scan3(int* __restrict__ rp, const int* __restrict__ boff) {
    int i = blockIdx.x * 256 + threadIdx.x;
    if (i < NN) rp[i] += boff[i >> 8];
    else if (i == NN) rp[NN] = NE;
}

__global__ __launch_bounds__(256) void k_scatter(const int* __restrict__ src, const int* __restrict__ dst,
                                                 const float* __restrict__ dinv, const int* __restrict__ rp,
                                                 int* __restrict__ cnt, int* __restrict__ col,
                                                 float* __restrict__ ewt) {
    int e = blockIdx.x * 256 + threadIdx.x;
    if (e >= NE) return;
    int s = src[e], d = dst[e];
    int pos = rp[d] + atomicAdd(&cnt[d], 1);
    col[pos] = s;
    ewt[pos] = dinv[s] * dinv[d];
}

// ---------------- lift: h = [tanh(x @ lift_w^T + b), ones] ----------------

__global__ __launch_bounds__(256) void k_lift(const float* __restrict__ x, const float* __restrict__ lw,
                                              const float* __restrict__ lb, float* __restrict__ h) {
    __shared__ float Wt[CIN][HH + 1];   // transposed + padded (no bank conflict)
    __shared__ float xs[4][CIN];
    for (int idx = threadIdx.x; idx < CIN * HH; idx += 256) {
        int c = idx >> 7, k = idx & 127;  // lw is [H][CIN] row-major
        Wt[k][c] = lw[idx];
    }
    int lane = threadIdx.x & 63, wid = threadIdx.x >> 6;
    int n = blockIdx.x * 4 + wid;         // grid exact: 12500*4 = 50000
    const float* xr = x + (size_t)n * CIN;
    xs[wid][lane] = xr[lane];
    xs[wid][HH + lane] = xr[HH + lane];
    __syncthreads();
    float acc = lb[lane];
#pragma unroll 8
    for (int k = 0; k < CIN; ++k) acc = fmaf(xs[wid][k], Wt[k][lane], acc);
    float* hr = h + (size_t)n * 128;
    hr[lane] = tanhf(acc);
    hr[HH + lane] = 1.0f;
}

// ---------------- layer kernels ----------------
// kA: Z1 = (rhs + DT*d*spmm(Z0))/diag, with Z0 = rhs/diag recomputed from h on the fly.

__global__ __launch_bounds__(256) void k_spmm1(const float* __restrict__ h, float* __restrict__ z1,
                                               const int* __restrict__ rp, const int* __restrict__ col,
                                               const float* __restrict__ ewt,
                                               const float* __restrict__ alpha, const float* __restrict__ beta,
                                               const float* __restrict__ dxp, const float* __restrict__ dyp,
                                               int l) {
    int lane = threadIdx.x & 63, wid = threadIdx.x >> 6;
    int n = blockIdx.x * 4 + wid;
    float a = alpha[l], b = beta[l], dx = dxp[l], dy = dyp[l];
    float idx_ = 1.0f / (1.0f + DTC * dx);
    float idy_ = 1.0f / (1.0f + DTC * dy);
    int e0 = rp[n], e1 = rp[n + 1];
    float accX = 0.f, accY = 0.f;
    for (int e = e0; e < e1; ++e) {
        int s = col[e];
        float wgt = ewt[e];
        const float* hs = h + (size_t)s * 128;
        float hx = hs[lane], hy = hs[HH + lane];
        float xy = hx * hy;
        float z0x = (hx + DTC * (a * hx - b * xy)) * idx_;
        float z0y = (hy + DTC * (b * xy - a * hy)) * idy_;
        accX = fmaf(wgt, z0x, accX);
        accY = fmaf(wgt, z0y, accY);
    }
    const float* hn = h + (size_t)n * 128;
    float hx = hn[lane], hy = hn[HH + lane];
    float xy = hx * hy;
    float rx = hx + DTC * (a * hx - b * xy);
    float ry = hy + DTC * (b * xy - a * hy);
    float* zn = z1 + (size_t)n * 128;
    zn[lane] = fmaf(DTC * dx, accX, rx) * idx_;
    zn[HH + lane] = fmaf(DTC * dy, accY, ry) * idy_;
}

// kB: Z2 = (rhs + DT*d*spmm(Z1))/diag; gate; LayerNorm; h updated in place.

__global__ __launch_bounds__(256) void k_spmm2(float* __restrict__ h, const float* __restrict__ z1,
                                               const int* __restrict__ rp, const int* __restrict__ col,
                                               const float* __restrict__ ewt,
                                               const float* __restrict__ alpha, const float* __restrict__ beta,
                                               const float* __restrict__ dxp, const float* __restrict__ dyp,
                                               const float* __restrict__ taup,
                                               const float* __restrict__ lnw, const float* __restrict__ lnb,
                                               int l) {
    int lane = threadIdx.x & 63, wid = threadIdx.x >> 6;
    int n = blockIdx.x * 4 + wid;
    float a = alpha[l], b = beta[l], dx = dxp[l], dy = dyp[l];
    float idx_ = 1.0f / (1.0f + DTC * dx);
    float idy_ = 1.0f / (1.0f + DTC * dy);
    int e0 = rp[n], e1 = rp[n + 1];
    float accX = 0.f, accY = 0.f;
    for (int e = e0; e < e1; ++e) {
        int s = col[e];
        float wgt = ewt[e];
        const float* zs = z1 + (size_t)s * 128;
        accX = fmaf(wgt, zs[lane], accX);
        accY = fmaf(wgt, zs[HH + lane], accY);
    }
    float* hn = h + (size_t)n * 128;
    float hx = hn[lane], hy = hn[HH + lane];
    float xy = hx * hy;
    float rx = hx + DTC * (a * hx - b * xy);
    float ry = hy + DTC * (b * xy - a * hy);
    float z2x = fmaf(DTC * dx, accX, rx) * idx_;
    float z2y = fmaf(DTC * dy, accY, ry) * idy_;
    float g = 1.0f / (1.0f + expf(-taup[l]));
    float nx = fmaf(g, z2x - hx, hx);   // (1-g)h + g*z
    float ny = fmaf(g, z2y - hy, hy);
    float s1 = nx + ny;
    float s2 = fmaf(nx, nx, ny * ny);
#pragma unroll
    for (int m = 1; m < 64; m <<= 1) {
        s1 += __shfl_xor(s1, m, 64);
        s2 += __shfl_xor(s2, m, 64);
    }
    float mean = s1 * (1.0f / 128.0f);
    float var = fmaf(-mean, mean, s2 * (1.0f / 128.0f));
    float rstd = rsqrtf(var + LNEPS);
    const float* lwr = lnw + (size_t)l * 128;
    const float* lbr = lnb + (size_t)l * 128;
    hn[lane] = fmaf((nx - mean) * rstd, lwr[lane], lbr[lane]);
    hn[HH + lane] = fmaf((ny - mean) * rstd, lwr[HH + lane], lbr[HH + lane]);
}

// ---------------- output head ----------------

__global__ __launch_bounds__(256) void k_out(const float* __restrict__ h, const float* __restrict__ ow,
                                             const float* __restrict__ ob, const float* __restrict__ lsp,
                                             float* __restrict__ out) {
    int lane = threadIdx.x & 63, wid = threadIdx.x >> 6;
    int n = blockIdx.x * 4 + wid;
    const float* hn = h + (size_t)n * 128;
    int j = lane < NCLS ? lane : 0;
    const float* wr = ow + j * HH;
    float acc = 0.f;
#pragma unroll 8
    for (int k = 0; k < HH; ++k) acc = fmaf(hn[k], wr[k], acc);
    if (lane < NCLS) out[(size_t)n * NCLS + lane] = fmaf(lsp[0], acc, ob[lane]);
}

// ---------------- launcher ----------------

extern "C" void kernel_launch(void* const* d_in, const int* in_sizes, int n_in,
                              void* d_out, int out_size, void* d_ws, size_t ws_size,
                              hipStream_t stream) {
    const float* x     = (const float*)d_in[0];
    const int*   ei    = (const int*)d_in[1];
    const float* lw    = (const float*)d_in[2];
    const float* lb    = (const float*)d_in[3];
    const float* alpha = (const float*)d_in[4];
    const float* beta  = (const float*)d_in[5];
    const float* dxp   = (const float*)d_in[6];
    const float* dyp   = (const float*)d_in[7];
    const float* taup  = (const float*)d_in[8];
    const float* lnw   = (const float*)d_in[9];
    const float* lnb   = (const float*)d_in[10];
    const float* ow    = (const float*)d_in[11];
    const float* ob    = (const float*)d_in[12];
    const float* lsp   = (const float*)d_in[13];
    float* out = (float*)d_out;

    const int* srcp = ei;
    const int* dstp = ei + NE;

    char* ws = (char*)d_ws;
    size_t o = 0;
    auto alloc = [&](size_t b) { size_t r = o; o += (b + 255) & ~(size_t)255; return r; };
    int*   row_ptr = (int*)(ws + alloc((NN + 1) * sizeof(int)));
    int*   deg     = (int*)(ws + alloc(NN * sizeof(int)));
    int*   cnt     = (int*)(ws + alloc(NN * sizeof(int)));
    float* dinv    = (float*)(ws + alloc(NN * sizeof(float)));
    int*   bsum    = (int*)(ws + alloc(256 * sizeof(int)));
    int*   boff    = (int*)(ws + alloc(256 * sizeof(int)));
    int*   col     = (int*)(ws + alloc((size_t)NE * sizeof(int)));
    float* ewt     = (float*)(ws + alloc((size_t)NE * sizeof(float)));
    float* hbuf    = (float*)(ws + alloc((size_t)NN * 128 * sizeof(float)));
    float* z1buf   = (float*)(ws + alloc((size_t)NN * 128 * sizeof(float)));

    hipMemsetAsync(deg, 0, NN * sizeof(int), stream);
    hipMemsetAsync(cnt, 0, NN * sizeof(int), stream);

    k_deg<<<(NE + 255) / 256, 256, 0, stream>>>(dstp, deg);
    k_dinv<<<(NN + 255) / 256, 256, 0, stream>>>(deg, dinv);
    k_scan1<<<NB_SCAN, 256, 0, stream>>>(deg, row_ptr, bsum);
    k_scan2<<<1, 256, 0, stream>>>(bsum, boff);
    k_scan3<<<NB_SCAN, 256, 0, stream>>>(row_ptr, boff);
    k_scatter<<<(NE + 255) / 256, 256, 0, stream>>>(srcp, dstp, dinv, row_ptr, cnt, col, ewt);

    k_lift<<<NN / 4, 256, 0, stream>>>(x, lw, lb, hbuf);

    for (int l = 0; l < NL; ++l) {
        k_spmm1<<<NN / 4, 256, 0, stream>>>(hbuf, z1buf, row_ptr, col, ewt, alpha, beta, dxp, dyp, l);
        k_spmm2<<<NN / 4, 256, 0, stream>>>(hbuf, z1buf, row_ptr, col, ewt, alpha, beta, dxp, dyp,
                                            taup, lnw, lnb, l);
    }

    k_out<<<NN / 4, 256, 0, stream>>>(hbuf, ow, ob, lsp, out);
}

// Round 2
// 1508.360 us; speedup vs baseline: 1.9163x; 1.9163x over previous
//
#include <hip/hip_runtime.h>

#define NN 50000
#define NE 800000
#define CIN 128
#define HH 64
#define NCLS 40
#define NL 15
#define DTC 0.1f
#define LNEPS 1e-5f
#define NB_SCAN 196   // ceil(50000/256)

// ---------------- bf16x2 pack/unpack ----------------

__device__ inline unsigned pack_bf2(float x, float y) {
    unsigned ux = __float_as_uint(x);
    unsigned uy = __float_as_uint(y);
    ux = (ux + 0x7fffu + ((ux >> 16) & 1u)) >> 16;   // RNE
    uy = (uy + 0x7fffu + ((uy >> 16) & 1u)) >> 16;
    return ux | (uy << 16);
}
__device__ inline float2 unpack_bf2(unsigned p) {
    float2 r;
    r.x = __uint_as_float(p << 16);
    r.y = __uint_as_float(p & 0xffff0000u);
    return r;
}

// ---------------- degree / normalization precompute ----------------

__global__ __launch_bounds__(256) void k_deg(const int* __restrict__ dst, int* __restrict__ deg) {
    int e = blockIdx.x * 256 + threadIdx.x;
    if (e < NE) atomicAdd(&deg[dst[e]], 1);
}

__global__ __launch_bounds__(256) void k_dinv(const int* __restrict__ deg, float* __restrict__ dinv) {
    int n = blockIdx.x * 256 + threadIdx.x;
    if (n < NN) dinv[n] = rsqrtf(fmaxf((float)deg[n], 1.0f));
}

__global__ __launch_bounds__(256) void k_scan1(const int* __restrict__ deg, int* __restrict__ rp,
                                               int* __restrict__ bsum) {
    int i = blockIdx.x * 256 + threadIdx.x;
    int v = (i < NN) ? deg[i] : 0;
    int lane = threadIdx.x & 63, wid = threadIdx.x >> 6;
    int inc = v;
#pragma unroll
    for (int d = 1; d < 64; d <<= 1) {
        int t = __shfl_up(inc, d, 64);
        if (lane >= d) inc += t;
    }
    __shared__ int wsum[4];
    if (lane == 63) wsum[wid] = inc;
    __syncthreads();
    int woff = 0;
#pragma unroll
    for (int w = 0; w < 4; ++w)
        if (w < wid) woff += wsum[w];
    if (i < NN) rp[i] = woff + inc - v;
    if (threadIdx.x == 255) bsum[blockIdx.x] = woff + inc;
}

__global__ __launch_bounds__(256) void k_scan2(const int* __restrict__ bsum, int* __restrict__ boff) {
    int t = threadIdx.x;
    int v = (t < NB_SCAN) ? bsum[t] : 0;
    int lane = t & 63, wid = t >> 6;
    int inc = v;
#pragma unroll
    for (int d = 1; d < 64; d <<= 1) {
        int tt = __shfl_up(inc, d, 64);
        if (lane >= d) inc += tt;
    }
    __shared__ int wsum[4];
    if (lane == 63) wsum[wid] = inc;
    __syncthreads();
    int woff = 0;
#pragma unroll
    for (int w = 0; w < 4; ++w)
        if (w < wid) woff += wsum[w];
    boff[t] = woff + inc - v;
}

__global__ __launch_bounds__(256) void k_scan3(int* __restrict__ rp, const int* __restrict__ boff) {
    int i = blockIdx.x * 256 + threadIdx.x;
    if (i < NN) rp[i] += boff[i >> 8];
    else if (i == NN) rp[NN] = NE;
}

__global__ __launch_bounds__(256) void k_scatter(const int* __restrict__ src, const int* __restrict__ dst,
                                                 const float* __restrict__ dinv, const int* __restrict__ rp,
                                                 int* __restrict__ cnt, int* __restrict__ col,
                                                 float* __restrict__ ewt) {
    int e = blockIdx.x * 256 + threadIdx.x;
    if (e >= NE) return;
    int s = src[e], d = dst[e];
    int pos = rp[d] + atomicAdd(&cnt[d], 1);
    col[pos] = s;
    ewt[pos] = dinv[s] * dinv[d];
}

// ---------------- lift: h = [tanh(x @ lift_w^T + b), ones]; also bf16 mirror ----

__global__ __launch_bounds__(256) void k_lift(const float* __restrict__ x, const float* __restrict__ lw,
                                              const float* __restrict__ lb, float* __restrict__ h,
                                              unsigned* __restrict__ hbf) {
    __shared__ float Wt[CIN][HH + 1];
    __shared__ float xs[4][CIN];
    for (int idx = threadIdx.x; idx < CIN * HH; idx += 256) {
        int c = idx >> 7, k = idx & 127;  // lw is [H][CIN] row-major
        Wt[k][c] = lw[idx];
    }
    int lane = threadIdx.x & 63, wid = threadIdx.x >> 6;
    int n = blockIdx.x * 4 + wid;
    const float* xr = x + (size_t)n * CIN;
    xs[wid][lane] = xr[lane];
    xs[wid][HH + lane] = xr[HH + lane];
    __syncthreads();
    float acc = lb[lane];
#pragma unroll 8
    for (int k = 0; k < CIN; ++k) acc = fmaf(xs[wid][k], Wt[k][lane], acc);
    float hx = tanhf(acc);
    float* hr = h + (size_t)n * 128;
    hr[lane] = hx;
    hr[HH + lane] = 1.0f;
    hbf[(size_t)n * HH + lane] = pack_bf2(hx, 1.0f);
}

// ---------------- layer kernels ----------------
// spmm1: gather packed h; compute z0 on the fly; z1 written packed bf16x2.

__global__ __launch_bounds__(256) void k_spmm1(const unsigned* __restrict__ hbf, unsigned* __restrict__ z1bf,
                                               const int* __restrict__ rp, const int* __restrict__ col,
                                               const float* __restrict__ ewt,
                                               const float* __restrict__ alpha, const float* __restrict__ beta,
                                               const float* __restrict__ dxp, const float* __restrict__ dyp,
                                               int l) {
    int lane = threadIdx.x & 63, wid = threadIdx.x >> 6;
    int n = blockIdx.x * 4 + wid;
    float a = alpha[l], b = beta[l], dx = dxp[l], dy = dyp[l];
    float idx_ = 1.0f / (1.0f + DTC * dx);
    float idy_ = 1.0f / (1.0f + DTC * dy);
    int e0 = rp[n], e1 = rp[n + 1];
    float accX = 0.f, accY = 0.f;
    int e = e0;
    // 4-deep pipelined gather
    for (; e + 3 < e1; e += 4) {
        int s0 = col[e], s1 = col[e + 1], s2 = col[e + 2], s3 = col[e + 3];
        float w0 = ewt[e], w1 = ewt[e + 1], w2 = ewt[e + 2], w3 = ewt[e + 3];
        unsigned g0 = hbf[(size_t)s0 * HH + lane];
        unsigned g1 = hbf[(size_t)s1 * HH + lane];
        unsigned g2 = hbf[(size_t)s2 * HH + lane];
        unsigned g3 = hbf[(size_t)s3 * HH + lane];
#pragma unroll
        for (int u = 0; u < 4; ++u) {
            unsigned g = u == 0 ? g0 : u == 1 ? g1 : u == 2 ? g2 : g3;
            float w = u == 0 ? w0 : u == 1 ? w1 : u == 2 ? w2 : w3;
            float2 hv = unpack_bf2(g);
            float xy = hv.x * hv.y;
            float z0x = (hv.x + DTC * (a * hv.x - b * xy)) * idx_;
            float z0y = (hv.y + DTC * (b * xy - a * hv.y)) * idy_;
            accX = fmaf(w, z0x, accX);
            accY = fmaf(w, z0y, accY);
        }
    }
    for (; e < e1; ++e) {
        int s = col[e];
        float w = ewt[e];
        float2 hv = unpack_bf2(hbf[(size_t)s * HH + lane]);
        float xy = hv.x * hv.y;
        float z0x = (hv.x + DTC * (a * hv.x - b * xy)) * idx_;
        float z0y = (hv.y + DTC * (b * xy - a * hv.y)) * idy_;
        accX = fmaf(w, z0x, accX);
        accY = fmaf(w, z0y, accY);
    }
    float2 hn = unpack_bf2(hbf[(size_t)n * HH + lane]);
    float xy = hn.x * hn.y;
    float rx = hn.x + DTC * (a * hn.x - b * xy);
    float ry = hn.y + DTC * (b * xy - a * hn.y);
    float z1x = fmaf(DTC * dx, accX, rx) * idx_;
    float z1y = fmaf(DTC * dy, accY, ry) * idy_;
    z1bf[(size_t)n * HH + lane] = pack_bf2(z1x, z1y);
}

// spmm2: gather packed z1; gate + LayerNorm; h (fp32) updated in place; hbf mirror.

__global__ __launch_bounds__(256) void k_spmm2(float* __restrict__ h, unsigned* __restrict__ hbf,
                                               const unsigned* __restrict__ z1bf,
                                               const int* __restrict__ rp, const int* __restrict__ col,
                                               const float* __restrict__ ewt,
                                               const float* __restrict__ alpha, const float* __restrict__ beta,
                                               const float* __restrict__ dxp, const float* __restrict__ dyp,
                                               const float* __restrict__ taup,
                                               const float* __restrict__ lnw, const float* __restrict__ lnb,
                                               int l) {
    int lane = threadIdx.x & 63, wid = threadIdx.x >> 6;
    int n = blockIdx.x * 4 + wid;
    float a = alpha[l], b = beta[l], dx = dxp[l], dy = dyp[l];
    float idx_ = 1.0f / (1.0f + DTC * dx);
    float idy_ = 1.0f / (1.0f + DTC * dy);
    int e0 = rp[n], e1 = rp[n + 1];
    float accX = 0.f, accY = 0.f;
    int e = e0;
    for (; e + 3 < e1; e += 4) {
        int s0 = col[e], s1 = col[e + 1], s2 = col[e + 2], s3 = col[e + 3];
        float w0 = ewt[e], w1 = ewt[e + 1], w2 = ewt[e + 2], w3 = ewt[e + 3];
        unsigned g0 = z1bf[(size_t)s0 * HH + lane];
        unsigned g1 = z1bf[(size_t)s1 * HH + lane];
        unsigned g2 = z1bf[(size_t)s2 * HH + lane];
        unsigned g3 = z1bf[(size_t)s3 * HH + lane];
#pragma unroll
        for (int u = 0; u < 4; ++u) {
            unsigned g = u == 0 ? g0 : u == 1 ? g1 : u == 2 ? g2 : g3;
            float w = u == 0 ? w0 : u == 1 ? w1 : u == 2 ? w2 : w3;
            float2 zv = unpack_bf2(g);
            accX = fmaf(w, zv.x, accX);
            accY = fmaf(w, zv.y, accY);
        }
    }
    for (; e < e1; ++e) {
        int s = col[e];
        float w = ewt[e];
        float2 zv = unpack_bf2(z1bf[(size_t)s * HH + lane]);
        accX = fmaf(w, zv.x, accX);
        accY = fmaf(w, zv.y, accY);
    }
    float* hn = h + (size_t)n * 128;
    float hx = hn[lane], hy = hn[HH + lane];
    float xy = hx * hy;
    float rx = hx + DTC * (a * hx - b * xy);
    float ry = hy + DTC * (b * xy - a * hy);
    float z2x = fmaf(DTC * dx, accX, rx) * idx_;
    float z2y = fmaf(DTC * dy, accY, ry) * idy_;
    float g = 1.0f / (1.0f + expf(-taup[l]));
    float nx = fmaf(g, z2x - hx, hx);
    float ny = fmaf(g, z2y - hy, hy);
    float s1 = nx + ny;
    float s2 = fmaf(nx, nx, ny * ny);
#pragma unroll
    for (int m = 1; m < 64; m <<= 1) {
        s1 += __shfl_xor(s1, m, 64);
        s2 += __shfl_xor(s2, m, 64);
    }
    float mean = s1 * (1.0f / 128.0f);
    float var = fmaf(-mean, mean, s2 * (1.0f / 128.0f));
    float rstd = rsqrtf(var + LNEPS);
    const float* lwr = lnw + (size_t)l * 128;
    const float* lbr = lnb + (size_t)l * 128;
    float ox = fmaf((nx - mean) * rstd, lwr[lane], lbr[lane]);
    float oy = fmaf((ny - mean) * rstd, lwr[HH + lane], lbr[HH + lane]);
    hn[lane] = ox;
    hn[HH + lane] = oy;
    hbf[(size_t)n * HH + lane] = pack_bf2(ox, oy);
}

// ---------------- output head ----------------

__global__ __launch_bounds__(256) void k_out(const float* __restrict__ h, const float* __restrict__ ow,
                                             const float* __restrict__ ob, const float* __restrict__ lsp,
                                             float* __restrict__ out) {
    int lane = threadIdx.x & 63, wid = threadIdx.x >> 6;
    int n = blockIdx.x * 4 + wid;
    const float* hn = h + (size_t)n * 128;
    int j = lane < NCLS ? lane : 0;
    const float* wr = ow + j * HH;
    float acc = 0.f;
#pragma unroll 8
    for (int k = 0; k < HH; ++k) acc = fmaf(hn[k], wr[k], acc);
    if (lane < NCLS) out[(size_t)n * NCLS + lane] = fmaf(lsp[0], acc, ob[lane]);
}

// ---------------- launcher ----------------

extern "C" void kernel_launch(void* const* d_in, const int* in_sizes, int n_in,
                              void* d_out, int out_size, void* d_ws, size_t ws_size,
                              hipStream_t stream) {
    const float* x     = (const float*)d_in[0];
    const int*   ei    = (const int*)d_in[1];
    const float* lw    = (const float*)d_in[2];
    const float* lb    = (const float*)d_in[3];
    const float* alpha = (const float*)d_in[4];
    const float* beta  = (const float*)d_in[5];
    const float* dxp   = (const float*)d_in[6];
    const float* dyp   = (const float*)d_in[7];
    const float* taup  = (const float*)d_in[8];
    const float* lnw   = (const float*)d_in[9];
    const float* lnb   = (const float*)d_in[10];
    const float* ow    = (const float*)d_in[11];
    const float* ob    = (const float*)d_in[12];
    const float* lsp   = (const float*)d_in[13];
    float* out = (float*)d_out;

    const int* srcp = ei;
    const int* dstp = ei + NE;

    char* ws = (char*)d_ws;
    size_t o = 0;
    auto alloc = [&](size_t b) { size_t r = o; o += (b + 255) & ~(size_t)255; return r; };
    int*      row_ptr = (int*)(ws + alloc((NN + 1) * sizeof(int)));
    int*      deg     = (int*)(ws + alloc(NN * sizeof(int)));
    int*      cnt     = (int*)(ws + alloc(NN * sizeof(int)));
    float*    dinv    = (float*)(ws + alloc(NN * sizeof(float)));
    int*      bsum    = (int*)(ws + alloc(256 * sizeof(int)));
    int*      boff    = (int*)(ws + alloc(256 * sizeof(int)));
    int*      col     = (int*)(ws + alloc((size_t)NE * sizeof(int)));
    float*    ewt     = (float*)(ws + alloc((size_t)NE * sizeof(float)));
    float*    hbuf    = (float*)(ws + alloc((size_t)NN * 128 * sizeof(float)));
    unsigned* hbf     = (unsigned*)(ws + alloc((size_t)NN * HH * sizeof(unsigned)));
    unsigned* z1bf    = (unsigned*)(ws + alloc((size_t)NN * HH * sizeof(unsigned)));

    hipMemsetAsync(deg, 0, NN * sizeof(int), stream);
    hipMemsetAsync(cnt, 0, NN * sizeof(int), stream);

    k_deg<<<(NE + 255) / 256, 256, 0, stream>>>(dstp, deg);
    k_dinv<<<(NN + 255) / 256, 256, 0, stream>>>(deg, dinv);
    k_scan1<<<NB_SCAN, 256, 0, stream>>>(deg, row_ptr, bsum);
    k_scan2<<<1, 256, 0, stream>>>(bsum, boff);
    k_scan3<<<NB_SCAN, 256, 0, stream>>>(row_ptr, boff);
    k_scatter<<<(NE + 255) / 256, 256, 0, stream>>>(srcp, dstp, dinv, row_ptr, cnt, col, ewt);

    k_lift<<<NN / 4, 256, 0, stream>>>(x, lw, lb, hbuf, hbf);

    for (int l = 0; l < NL; ++l) {
        k_spmm1<<<NN / 4, 256, 0, stream>>>(hbf, z1bf, row_ptr, col, ewt, alpha, beta, dxp, dyp, l);
        k_spmm2<<<NN / 4, 256, 0, stream>>>(hbuf, hbf, z1bf, row_ptr, col, ewt, alpha, beta, dxp, dyp,
                                            taup, lnw, lnb, l);
    }

    k_out<<<NN / 4, 256, 0, stream>>>(hbuf, ow, ob, lsp, out);
}

// Round 3
// 1457.973 us; speedup vs baseline: 1.9825x; 1.0346x over previous
//
#include <hip/hip_runtime.h>

#define NN 50000
#define NE 800000
#define CIN 128
#define HH 64
#define NCLS 40
#define NL 15
#define DTC 0.1f
#define LNEPS 1e-5f
#define NB_SCAN 196   // ceil(50000/256)

// ---------------- bf16x2 pack/unpack ----------------

__device__ inline unsigned pack_bf2(float x, float y) {
    unsigned ux = __float_as_uint(x);
    unsigned uy = __float_as_uint(y);
    ux = (ux + 0x7fffu + ((ux >> 16) & 1u)) >> 16;   // RNE
    uy = (uy + 0x7fffu + ((uy >> 16) & 1u)) >> 16;
    return ux | (uy << 16);
}
__device__ inline float2 unpack_bf2(unsigned p) {
    float2 r;
    r.x = __uint_as_float(p << 16);
    r.y = __uint_as_float(p & 0xffff0000u);
    return r;
}

// ---------------- degree / normalization precompute ----------------

__global__ __launch_bounds__(256) void k_deg(const int* __restrict__ dst, int* __restrict__ deg) {
    int e = blockIdx.x * 256 + threadIdx.x;
    if (e < NE) atomicAdd(&deg[dst[e]], 1);
}

__global__ __launch_bounds__(256) void k_dinv(const int* __restrict__ deg, float* __restrict__ dinv) {
    int n = blockIdx.x * 256 + threadIdx.x;
    if (n < NN) dinv[n] = rsqrtf(fmaxf((float)deg[n], 1.0f));
}

__global__ __launch_bounds__(256) void k_scan1(const int* __restrict__ deg, int* __restrict__ rp,
                                               int* __restrict__ bsum) {
    int i = blockIdx.x * 256 + threadIdx.x;
    int v = (i < NN) ? deg[i] : 0;
    int lane = threadIdx.x & 63, wid = threadIdx.x >> 6;
    int inc = v;
#pragma unroll
    for (int d = 1; d < 64; d <<= 1) {
        int t = __shfl_up(inc, d, 64);
        if (lane >= d) inc += t;
    }
    __shared__ int wsum[4];
    if (lane == 63) wsum[wid] = inc;
    __syncthreads();
    int woff = 0;
#pragma unroll
    for (int w = 0; w < 4; ++w)
        if (w < wid) woff += wsum[w];
    if (i < NN) rp[i] = woff + inc - v;
    if (threadIdx.x == 255) bsum[blockIdx.x] = woff + inc;
}

__global__ __launch_bounds__(256) void k_scan2(const int* __restrict__ bsum, int* __restrict__ boff) {
    int t = threadIdx.x;
    int v = (t < NB_SCAN) ? bsum[t] : 0;
    int lane = t & 63, wid = t >> 6;
    int inc = v;
#pragma unroll
    for (int d = 1; d < 64; d <<= 1) {
        int tt = __shfl_up(inc, d, 64);
        if (lane >= d) inc += tt;
    }
    __shared__ int wsum[4];
    if (lane == 63) wsum[wid] = inc;
    __syncthreads();
    int woff = 0;
#pragma unroll
    for (int w = 0; w < 4; ++w)
        if (w < wid) woff += wsum[w];
    boff[t] = woff + inc - v;
}

__global__ __launch_bounds__(256) void k_scan3(int* __restrict__ rp, const int* __restrict__ boff) {
    int i = blockIdx.x * 256 + threadIdx.x;
    if (i < NN) rp[i] += boff[i >> 8];
    else if (i == NN) rp[NN] = NE;
}

__global__ __launch_bounds__(256) void k_scatter(const int* __restrict__ src, const int* __restrict__ dst,
                                                 const float* __restrict__ dinv, const int* __restrict__ rp,
                                                 int* __restrict__ cnt, int* __restrict__ col,
                                                 float* __restrict__ ewt) {
    int e = blockIdx.x * 256 + threadIdx.x;
    if (e >= NE) return;
    int s = src[e], d = dst[e];
    int pos = rp[d] + atomicAdd(&cnt[d], 1);
    col[pos] = s;
    ewt[pos] = dinv[s] * dinv[d];
}

// ---------------- lift: h = [tanh(x @ lift_w^T + b), ones]; 16 nodes/block ----

#define LIFT_NPB 16

__global__ __launch_bounds__(256) void k_lift(const float* __restrict__ x, const float* __restrict__ lw,
                                              const float* __restrict__ lb, float* __restrict__ h,
                                              unsigned* __restrict__ hbf) {
    __shared__ float Wt[CIN][HH + 1];
    __shared__ float xs[LIFT_NPB][CIN];
    int t = threadIdx.x;
    for (int idx = t; idx < CIN * HH; idx += 256) {
        int c = idx >> 7, k = idx & 127;  // lw is [H][CIN] row-major
        Wt[k][c] = lw[idx];
    }
    int n0 = blockIdx.x * LIFT_NPB;      // 3125 * 16 = 50000 exact
#pragma unroll
    for (int i = 0; i < LIFT_NPB * CIN / 256; ++i) {
        int idx = i * 256 + t;
        int r = idx >> 7, c = idx & 127;
        xs[r][c] = x[(size_t)(n0 + r) * CIN + c];
    }
    __syncthreads();
    int lane = t & 63, wid = t >> 6;
    float bias = lb[lane];
#pragma unroll
    for (int i = 0; i < 4; ++i) {
        int nl = wid * 4 + i;
        float acc = bias;
#pragma unroll 8
        for (int k = 0; k < CIN; ++k) acc = fmaf(xs[nl][k], Wt[k][lane], acc);
        float hx = tanhf(acc);
        int n = n0 + nl;
        float* hr = h + (size_t)n * 128;
        hr[lane] = hx;
        hr[HH + lane] = 1.0f;
        hbf[(size_t)n * HH + lane] = pack_bf2(hx, 1.0f);
    }
}

// ---------------- layer kernels ----------------
// spmm1: gather packed h; compute z0 on the fly; z1 written packed bf16x2.

__global__ __launch_bounds__(256) void k_spmm1(const unsigned* __restrict__ hbf, unsigned* __restrict__ z1bf,
                                               const int* __restrict__ rp, const int* __restrict__ col,
                                               const float* __restrict__ ewt,
                                               const float* __restrict__ alpha, const float* __restrict__ beta,
                                               const float* __restrict__ dxp, const float* __restrict__ dyp,
                                               int l) {
    int lane = threadIdx.x & 63, wid = threadIdx.x >> 6;
    int n = blockIdx.x * 4 + wid;
    float a = alpha[l], b = beta[l], dx = dxp[l], dy = dyp[l];
    float idx_ = 1.0f / (1.0f + DTC * dx);
    float idy_ = 1.0f / (1.0f + DTC * dy);
    int e0 = rp[n], e1 = rp[n + 1];
    float accX = 0.f, accY = 0.f;
    int e = e0;
    for (; e + 8 <= e1; e += 8) {
        int s[8]; float w[8]; unsigned g[8];
#pragma unroll
        for (int u = 0; u < 8; ++u) { s[u] = col[e + u]; w[u] = ewt[e + u]; }
#pragma unroll
        for (int u = 0; u < 8; ++u) g[u] = hbf[(size_t)s[u] * HH + lane];
#pragma unroll
        for (int u = 0; u < 8; ++u) {
            float2 hv = unpack_bf2(g[u]);
            float xy = hv.x * hv.y;
            float z0x = (hv.x + DTC * (a * hv.x - b * xy)) * idx_;
            float z0y = (hv.y + DTC * (b * xy - a * hv.y)) * idy_;
            accX = fmaf(w[u], z0x, accX);
            accY = fmaf(w[u], z0y, accY);
        }
    }
    for (; e < e1; ++e) {
        int s = col[e];
        float w = ewt[e];
        float2 hv = unpack_bf2(hbf[(size_t)s * HH + lane]);
        float xy = hv.x * hv.y;
        float z0x = (hv.x + DTC * (a * hv.x - b * xy)) * idx_;
        float z0y = (hv.y + DTC * (b * xy - a * hv.y)) * idy_;
        accX = fmaf(w, z0x, accX);
        accY = fmaf(w, z0y, accY);
    }
    float2 hn = unpack_bf2(hbf[(size_t)n * HH + lane]);
    float xy = hn.x * hn.y;
    float rx = hn.x + DTC * (a * hn.x - b * xy);
    float ry = hn.y + DTC * (b * xy - a * hn.y);
    float z1x = fmaf(DTC * dx, accX, rx) * idx_;
    float z1y = fmaf(DTC * dy, accY, ry) * idy_;
    z1bf[(size_t)n * HH + lane] = pack_bf2(z1x, z1y);
}

// spmm2: gather packed z1; gate + LayerNorm; h (fp32) updated in place; hbf mirror.

__global__ __launch_bounds__(256) void k_spmm2(float* __restrict__ h, unsigned* __restrict__ hbf,
                                               const unsigned* __restrict__ z1bf,
                                               const int* __restrict__ rp, const int* __restrict__ col,
                                               const float* __restrict__ ewt,
                                               const float* __restrict__ alpha, const float* __restrict__ beta,
                                               const float* __restrict__ dxp, const float* __restrict__ dyp,
                                               const float* __restrict__ taup,
                                               const float* __restrict__ lnw, const float* __restrict__ lnb,
                                               int l) {
    int lane = threadIdx.x & 63, wid = threadIdx.x >> 6;
    int n = blockIdx.x * 4 + wid;
    float a = alpha[l], b = beta[l], dx = dxp[l], dy = dyp[l];
    float idx_ = 1.0f / (1.0f + DTC * dx);
    float idy_ = 1.0f / (1.0f + DTC * dy);
    int e0 = rp[n], e1 = rp[n + 1];
    float accX = 0.f, accY = 0.f;
    int e = e0;
    for (; e + 8 <= e1; e += 8) {
        int s[8]; float w[8]; unsigned g[8];
#pragma unroll
        for (int u = 0; u < 8; ++u) { s[u] = col[e + u]; w[u] = ewt[e + u]; }
#pragma unroll
        for (int u = 0; u < 8; ++u) g[u] = z1bf[(size_t)s[u] * HH + lane];
#pragma unroll
        for (int u = 0; u < 8; ++u) {
            float2 zv = unpack_bf2(g[u]);
            accX = fmaf(w[u], zv.x, accX);
            accY = fmaf(w[u], zv.y, accY);
        }
    }
    for (; e < e1; ++e) {
        int s = col[e];
        float w = ewt[e];
        float2 zv = unpack_bf2(z1bf[(size_t)s * HH + lane]);
        accX = fmaf(w, zv.x, accX);
        accY = fmaf(w, zv.y, accY);
    }
    float* hn = h + (size_t)n * 128;
    float hx = hn[lane], hy = hn[HH + lane];
    float xy = hx * hy;
    float rx = hx + DTC * (a * hx - b * xy);
    float ry = hy + DTC * (b * xy - a * hy);
    float z2x = fmaf(DTC * dx, accX, rx) * idx_;
    float z2y = fmaf(DTC * dy, accY, ry) * idy_;
    float g = 1.0f / (1.0f + expf(-taup[l]));
    float nx = fmaf(g, z2x - hx, hx);
    float ny = fmaf(g, z2y - hy, hy);
    float s1 = nx + ny;
    float s2 = fmaf(nx, nx, ny * ny);
#pragma unroll
    for (int m = 1; m < 64; m <<= 1) {
        s1 += __shfl_xor(s1, m, 64);
        s2 += __shfl_xor(s2, m, 64);
    }
    float mean = s1 * (1.0f / 128.0f);
    float var = fmaf(-mean, mean, s2 * (1.0f / 128.0f));
    float rstd = rsqrtf(var + LNEPS);
    const float* lwr = lnw + (size_t)l * 128;
    const float* lbr = lnb + (size_t)l * 128;
    float ox = fmaf((nx - mean) * rstd, lwr[lane], lbr[lane]);
    float oy = fmaf((ny - mean) * rstd, lwr[HH + lane], lbr[HH + lane]);
    hn[lane] = ox;
    hn[HH + lane] = oy;
    hbf[(size_t)n * HH + lane] = pack_bf2(ox, oy);
}

// ---------------- output head: LDS-staged, thread-per-output ----------------

__global__ __launch_bounds__(256) void k_out(const float* __restrict__ h, const float* __restrict__ ow,
                                             const float* __restrict__ ob, const float* __restrict__ lsp,
                                             float* __restrict__ out) {
    __shared__ float hs[64][65];
    __shared__ float ows[NCLS][65];
    __shared__ float obs[NCLS];
    int t = threadIdx.x;
    int n0 = blockIdx.x * 64;
#pragma unroll
    for (int i = 0; i < 16; ++i) {
        int idx = i * 256 + t;
        int r = idx >> 6, c = idx & 63;
        int n = n0 + r;
        hs[r][c] = (n < NN) ? h[(size_t)n * 128 + c] : 0.f;   // X half only
    }
#pragma unroll
    for (int i = 0; i < 10; ++i) {
        int idx = i * 256 + t;
        int j = idx >> 6, c = idx & 63;
        ows[j][c] = ow[j * HH + c];
    }
    if (t < NCLS) obs[t] = ob[t];
    __syncthreads();
    float ls = lsp[0];
#pragma unroll
    for (int i = 0; i < 10; ++i) {
        int o = i * 256 + t;          // 0..2559
        int nl = o / NCLS;
        int j = o - nl * NCLS;
        float acc = 0.f;
#pragma unroll 8
        for (int k = 0; k < HH; ++k) acc = fmaf(hs[nl][k], ows[j][k], acc);
        int n = n0 + nl;
        if (n < NN) out[(size_t)n * NCLS + j] = fmaf(ls, acc, obs[j]);
    }
}

// ---------------- launcher ----------------

extern "C" void kernel_launch(void* const* d_in, const int* in_sizes, int n_in,
                              void* d_out, int out_size, void* d_ws, size_t ws_size,
                              hipStream_t stream) {
    const float* x     = (const float*)d_in[0];
    const int*   ei    = (const int*)d_in[1];
    const float* lw    = (const float*)d_in[2];
    const float* lb    = (const float*)d_in[3];
    const float* alpha = (const float*)d_in[4];
    const float* beta  = (const float*)d_in[5];
    const float* dxp   = (const float*)d_in[6];
    const float* dyp   = (const float*)d_in[7];
    const float* taup  = (const float*)d_in[8];
    const float* lnw   = (const float*)d_in[9];
    const float* lnb   = (const float*)d_in[10];
    const float* ow    = (const float*)d_in[11];
    const float* ob    = (const float*)d_in[12];
    const float* lsp   = (const float*)d_in[13];
    float* out = (float*)d_out;

    const int* srcp = ei;
    const int* dstp = ei + NE;

    char* ws = (char*)d_ws;
    size_t o = 0;
    auto alloc = [&](size_t b) { size_t r = o; o += (b + 255) & ~(size_t)255; return r; };
    int*      row_ptr = (int*)(ws + alloc((NN + 1) * sizeof(int)));
    int*      deg     = (int*)(ws + alloc(NN * sizeof(int)));
    int*      cnt     = (int*)(ws + alloc(NN * sizeof(int)));
    float*    dinv    = (float*)(ws + alloc(NN * sizeof(float)));
    int*      bsum    = (int*)(ws + alloc(256 * sizeof(int)));
    int*      boff    = (int*)(ws + alloc(256 * sizeof(int)));
    int*      col     = (int*)(ws + alloc((size_t)NE * sizeof(int)));
    float*    ewt     = (float*)(ws + alloc((size_t)NE * sizeof(float)));
    float*    hbuf    = (float*)(ws + alloc((size_t)NN * 128 * sizeof(float)));
    unsigned* hbf     = (unsigned*)(ws + alloc((size_t)NN * HH * sizeof(unsigned)));
    unsigned* z1bf    = (unsigned*)(ws + alloc((size_t)NN * HH * sizeof(unsigned)));

    hipMemsetAsync(deg, 0, NN * sizeof(int), stream);
    hipMemsetAsync(cnt, 0, NN * sizeof(int), stream);

    k_deg<<<(NE + 255) / 256, 256, 0, stream>>>(dstp, deg);
    k_dinv<<<(NN + 255) / 256, 256, 0, stream>>>(deg, dinv);
    k_scan1<<<NB_SCAN, 256, 0, stream>>>(deg, row_ptr, bsum);
    k_scan2<<<1, 256, 0, stream>>>(bsum, boff);
    k_scan3<<<NB_SCAN, 256, 0, stream>>>(row_ptr, boff);
    k_scatter<<<(NE + 255) / 256, 256, 0, stream>>>(srcp, dstp, dinv, row_ptr, cnt, col, ewt);

    k_lift<<<NN / LIFT_NPB, 256, 0, stream>>>(x, lw, lb, hbuf, hbf);

    for (int l = 0; l < NL; ++l) {
        k_spmm1<<<NN / 4, 256, 0, stream>>>(hbf, z1bf, row_ptr, col, ewt, alpha, beta, dxp, dyp, l);
        k_spmm2<<<NN / 4, 256, 0, stream>>>(hbuf, hbf, z1bf, row_ptr, col, ewt, alpha, beta, dxp, dyp,
                                            taup, lnw, lnb, l);
    }

    k_out<<<(NN + 63) / 64, 256, 0, stream>>>(hbuf, ow, ob, lsp, out);
}

// Round 4
// 1354.987 us; speedup vs baseline: 2.1332x; 1.0760x over previous
//
#include <hip/hip_runtime.h>

#define NN 50000
#define NE 800000
#define CIN 128
#define HH 64
#define NCLS 40
#define NL 15
#define DTC 0.1f
#define LNEPS 1e-5f
#define NB_SCAN 196   // ceil(50000/256)

typedef float f32x2 __attribute__((ext_vector_type(2)));

// ---------------- bf16x2 / fp8x2 pack-unpack ----------------

__device__ inline unsigned pack_bf2(float x, float y) {
    unsigned ux = __float_as_uint(x);
    unsigned uy = __float_as_uint(y);
    ux = (ux + 0x7fffu + ((ux >> 16) & 1u)) >> 16;   // RNE
    uy = (uy + 0x7fffu + ((uy >> 16) & 1u)) >> 16;
    return ux | (uy << 16);
}
__device__ inline float2 unpack_bf2(unsigned p) {
    float2 r;
    r.x = __uint_as_float(p << 16);
    r.y = __uint_as_float(p & 0xffff0000u);
    return r;
}
// OCP e4m3 hw conversion (gfx950): pack (x,y) into low 16 bits
__device__ inline unsigned short pack_fp8x2(float x, float y) {
    int r = __builtin_amdgcn_cvt_pk_fp8_f32(x, y, 0, false);
    return (unsigned short)(r & 0xffff);
}
__device__ inline float2 unpack_fp8x2(unsigned short p) {
    f32x2 v = __builtin_amdgcn_cvt_pk_f32_fp8((int)(unsigned)p, false);
    float2 r; r.x = v.x; r.y = v.y; return r;
}

// ---------------- degree / normalization precompute ----------------

__global__ __launch_bounds__(256) void k_deg(const int* __restrict__ dst, int* __restrict__ deg) {
    int e = blockIdx.x * 256 + threadIdx.x;
    if (e < NE) atomicAdd(&deg[dst[e]], 1);
}

__global__ __launch_bounds__(256) void k_scan1(const int* __restrict__ deg, int* __restrict__ rp,
                                               int* __restrict__ bsum, float* __restrict__ dinv) {
    int i = blockIdx.x * 256 + threadIdx.x;
    int v = (i < NN) ? deg[i] : 0;
    if (i < NN) dinv[i] = rsqrtf(fmaxf((float)v, 1.0f));
    int lane = threadIdx.x & 63, wid = threadIdx.x >> 6;
    int inc = v;
#pragma unroll
    for (int d = 1; d < 64; d <<= 1) {
        int t = __shfl_up(inc, d, 64);
        if (lane >= d) inc += t;
    }
    __shared__ int wsum[4];
    if (lane == 63) wsum[wid] = inc;
    __syncthreads();
    int woff = 0;
#pragma unroll
    for (int w = 0; w < 4; ++w)
        if (w < wid) woff += wsum[w];
    if (i < NN) rp[i] = woff + inc - v;
    if (threadIdx.x == 255) bsum[blockIdx.x] = woff + inc;
}

__global__ __launch_bounds__(256) void k_scan2(const int* __restrict__ bsum, int* __restrict__ boff) {
    int t = threadIdx.x;
    int v = (t < NB_SCAN) ? bsum[t] : 0;
    int lane = t & 63, wid = t >> 6;
    int inc = v;
#pragma unroll
    for (int d = 1; d < 64; d <<= 1) {
        int tt = __shfl_up(inc, d, 64);
        if (lane >= d) inc += tt;
    }
    __shared__ int wsum[4];
    if (lane == 63) wsum[wid] = inc;
    __syncthreads();
    int woff = 0;
#pragma unroll
    for (int w = 0; w < 4; ++w)
        if (w < wid) woff += wsum[w];
    boff[t] = woff + inc - v;
}

__global__ __launch_bounds__(256) void k_scan3(int* __restrict__ rp, const int* __restrict__ boff) {
    int i = blockIdx.x * 256 + threadIdx.x;
    if (i < NN) rp[i] += boff[i >> 8];
    else if (i == NN) rp[NN] = NE;
}

// interleaved edge record: {src, ewt-bits} -> single 8B store
__global__ __launch_bounds__(256) void k_scatter(const int* __restrict__ src, const int* __restrict__ dst,
                                                 const float* __restrict__ dinv, const int* __restrict__ rp,
                                                 int* __restrict__ cnt, uint2* __restrict__ edges) {
    int e = blockIdx.x * 256 + threadIdx.x;
    if (e >= NE) return;
    int s = src[e], d = dst[e];
    int pos = rp[d] + atomicAdd(&cnt[d], 1);
    uint2 rec;
    rec.x = (unsigned)s;
    rec.y = __float_as_uint(dinv[s] * dinv[d]);
    edges[pos] = rec;
}

// ---------------- lift: h = [tanh(x @ lift_w^T + b), ones] ----------------
// W staged bf16-packed (k-pairs) -> half the LDS + half the ds_reads.

#define LIFT_NPB 16

__global__ __launch_bounds__(256) void k_lift(const float* __restrict__ x, const float* __restrict__ lw,
                                              const float* __restrict__ lb, float* __restrict__ h,
                                              unsigned short* __restrict__ hbf8) {
    __shared__ unsigned Wt2[CIN / 2][HH + 1];   // Wt2[kk][c] = bf16(W[c][2kk]) | bf16(W[c][2kk+1])<<16
    __shared__ float xs[LIFT_NPB][CIN];
    int t = threadIdx.x;
    for (int idx = t; idx < (CIN / 2) * HH; idx += 256) {
        int c = idx & 63, kk = idx >> 6;
        Wt2[kk][c] = pack_bf2(lw[c * CIN + 2 * kk], lw[c * CIN + 2 * kk + 1]);
    }
    int n0 = blockIdx.x * LIFT_NPB;      // 3125 * 16 = 50000 exact
#pragma unroll
    for (int i = 0; i < LIFT_NPB * CIN / 256; ++i) {
        int idx = i * 256 + t;
        int r = idx >> 7, c = idx & 127;
        xs[r][c] = x[(size_t)(n0 + r) * CIN + c];
    }
    __syncthreads();
    int lane = t & 63, wid = t >> 6;
    float bias = lb[lane];
#pragma unroll
    for (int i = 0; i < 4; ++i) {
        int nl = wid * 4 + i;
        float acc0 = 0.f, acc1 = 0.f;
        const float2* xr = (const float2*)&xs[nl][0];
#pragma unroll 8
        for (int kk = 0; kk < CIN / 2; ++kk) {
            float2 xv = xr[kk];
            float2 wv = unpack_bf2(Wt2[kk][lane]);
            acc0 = fmaf(xv.x, wv.x, acc0);
            acc1 = fmaf(xv.y, wv.y, acc1);
        }
        float hx = tanhf(bias + acc0 + acc1);
        int n = n0 + nl;
        float* hr = h + (size_t)n * 128;
        hr[lane] = hx;
        hr[HH + lane] = 1.0f;
        hbf8[(size_t)n * HH + lane] = pack_fp8x2(hx, 1.0f);
    }
}

// ---------------- layer kernels (fp8 gathers) ----------------

__global__ __launch_bounds__(256) void k_spmm1(const float* __restrict__ h,
                                               const unsigned short* __restrict__ hbf8,
                                               unsigned short* __restrict__ z1bf8,
                                               const int* __restrict__ rp, const uint2* __restrict__ edges,
                                               const float* __restrict__ alpha, const float* __restrict__ beta,
                                               const float* __restrict__ dxp, const float* __restrict__ dyp,
                                               int l) {
    int lane = threadIdx.x & 63, wid = threadIdx.x >> 6;
    int n = blockIdx.x * 4 + wid;
    float a = alpha[l], b = beta[l], dx = dxp[l], dy = dyp[l];
    float idx_ = 1.0f / (1.0f + DTC * dx);
    float idy_ = 1.0f / (1.0f + DTC * dy);
    int e0 = rp[n], e1 = rp[n + 1];
    float accX = 0.f, accY = 0.f;
    int e = e0;
    for (; e + 8 <= e1; e += 8) {
        uint2 ed[8]; unsigned short g[8];
#pragma unroll
        for (int u = 0; u < 8; ++u) ed[u] = edges[e + u];
#pragma unroll
        for (int u = 0; u < 8; ++u) g[u] = hbf8[(size_t)ed[u].x * HH + lane];
#pragma unroll
        for (int u = 0; u < 8; ++u) {
            float w = __uint_as_float(ed[u].y);
            float2 hv = unpack_fp8x2(g[u]);
            float xy = hv.x * hv.y;
            float z0x = (hv.x + DTC * (a * hv.x - b * xy)) * idx_;
            float z0y = (hv.y + DTC * (b * xy - a * hv.y)) * idy_;
            accX = fmaf(w, z0x, accX);
            accY = fmaf(w, z0y, accY);
        }
    }
    for (; e < e1; ++e) {
        uint2 ed = edges[e];
        float w = __uint_as_float(ed.y);
        float2 hv = unpack_fp8x2(hbf8[(size_t)ed.x * HH + lane]);
        float xy = hv.x * hv.y;
        float z0x = (hv.x + DTC * (a * hv.x - b * xy)) * idx_;
        float z0y = (hv.y + DTC * (b * xy - a * hv.y)) * idy_;
        accX = fmaf(w, z0x, accX);
        accY = fmaf(w, z0y, accY);
    }
    // rhs from exact fp32 own-h
    const float* hn = h + (size_t)n * 128;
    float hx = hn[lane], hy = hn[HH + lane];
    float xy = hx * hy;
    float rx = hx + DTC * (a * hx - b * xy);
    float ry = hy + DTC * (b * xy - a * hy);
    float z1x = fmaf(DTC * dx, accX, rx) * idx_;
    float z1y = fmaf(DTC * dy, accY, ry) * idy_;
    z1bf8[(size_t)n * HH + lane] = pack_fp8x2(z1x, z1y);
}

__global__ __launch_bounds__(256) void k_spmm2(float* __restrict__ h, unsigned short* __restrict__ hbf8,
                                               const unsigned short* __restrict__ z1bf8,
                                               const int* __restrict__ rp, const uint2* __restrict__ edges,
                                               const float* __restrict__ alpha, const float* __restrict__ beta,
                                               const float* __restrict__ dxp, const float* __restrict__ dyp,
                                               const float* __restrict__ taup,
                                               const float* __restrict__ lnw, const float* __restrict__ lnb,
                                               int l) {
    int lane = threadIdx.x & 63, wid = threadIdx.x >> 6;
    int n = blockIdx.x * 4 + wid;
    float a = alpha[l], b = beta[l], dx = dxp[l], dy = dyp[l];
    float idx_ = 1.0f / (1.0f + DTC * dx);
    float idy_ = 1.0f / (1.0f + DTC * dy);
    int e0 = rp[n], e1 = rp[n + 1];
    float accX = 0.f, accY = 0.f;
    int e = e0;
    for (; e + 8 <= e1; e += 8) {
        uint2 ed[8]; unsigned short g[8];
#pragma unroll
        for (int u = 0; u < 8; ++u) ed[u] = edges[e + u];
#pragma unroll
        for (int u = 0; u < 8; ++u) g[u] = z1bf8[(size_t)ed[u].x * HH + lane];
#pragma unroll
        for (int u = 0; u < 8; ++u) {
            float w = __uint_as_float(ed[u].y);
            float2 zv = unpack_fp8x2(g[u]);
            accX = fmaf(w, zv.x, accX);
            accY = fmaf(w, zv.y, accY);
        }
    }
    for (; e < e1; ++e) {
        uint2 ed = edges[e];
        float w = __uint_as_float(ed.y);
        float2 zv = unpack_fp8x2(z1bf8[(size_t)ed.x * HH + lane]);
        accX = fmaf(w, zv.x, accX);
        accY = fmaf(w, zv.y, accY);
    }
    float* hn = h + (size_t)n * 128;
    float hx = hn[lane], hy = hn[HH + lane];
    float xy = hx * hy;
    float rx = hx + DTC * (a * hx - b * xy);
    float ry = hy + DTC * (b * xy - a * hy);
    float z2x = fmaf(DTC * dx, accX, rx) * idx_;
    float z2y = fmaf(DTC * dy, accY, ry) * idy_;
    float g = 1.0f / (1.0f + expf(-taup[l]));
    float nx = fmaf(g, z2x - hx, hx);
    float ny = fmaf(g, z2y - hy, hy);
    float s1 = nx + ny;
    float s2 = fmaf(nx, nx, ny * ny);
#pragma unroll
    for (int m = 1; m < 64; m <<= 1) {
        s1 += __shfl_xor(s1, m, 64);
        s2 += __shfl_xor(s2, m, 64);
    }
    float mean = s1 * (1.0f / 128.0f);
    float var = fmaf(-mean, mean, s2 * (1.0f / 128.0f));
    float rstd = rsqrtf(var + LNEPS);
    const float* lwr = lnw + (size_t)l * 128;
    const float* lbr = lnb + (size_t)l * 128;
    float ox = fmaf((nx - mean) * rstd, lwr[lane], lbr[lane]);
    float oy = fmaf((ny - mean) * rstd, lwr[HH + lane], lbr[HH + lane]);
    hn[lane] = ox;
    hn[HH + lane] = oy;
    hbf8[(size_t)n * HH + lane] = pack_fp8x2(ox, oy);
}

// ---------------- output head: LDS-staged, thread-per-output ----------------

__global__ __launch_bounds__(256) void k_out(const float* __restrict__ h, const float* __restrict__ ow,
                                             const float* __restrict__ ob, const float* __restrict__ lsp,
                                             float* __restrict__ out) {
    __shared__ float hs[64][65];
    __shared__ float ows[NCLS][65];
    __shared__ float obs[NCLS];
    int t = threadIdx.x;
    int n0 = blockIdx.x * 64;
#pragma unroll
    for (int i = 0; i < 16; ++i) {
        int idx = i * 256 + t;
        int r = idx >> 6, c = idx & 63;
        int n = n0 + r;
        hs[r][c] = (n < NN) ? h[(size_t)n * 128 + c] : 0.f;   // X half only
    }
#pragma unroll
    for (int i = 0; i < 10; ++i) {
        int idx = i * 256 + t;
        int j = idx >> 6, c = idx & 63;
        ows[j][c] = ow[j * HH + c];
    }
    if (t < NCLS) obs[t] = ob[t];
    __syncthreads();
    float ls = lsp[0];
#pragma unroll
    for (int i = 0; i < 10; ++i) {
        int o = i * 256 + t;          // 0..2559
        int nl = o / NCLS;
        int j = o - nl * NCLS;
        float acc = 0.f;
#pragma unroll 8
        for (int k = 0; k < HH; ++k) acc = fmaf(hs[nl][k], ows[j][k], acc);
        int n = n0 + nl;
        if (n < NN) out[(size_t)n * NCLS + j] = fmaf(ls, acc, obs[j]);
    }
}

// ---------------- launcher ----------------

extern "C" void kernel_launch(void* const* d_in, const int* in_sizes, int n_in,
                              void* d_out, int out_size, void* d_ws, size_t ws_size,
                              hipStream_t stream) {
    const float* x     = (const float*)d_in[0];
    const int*   ei    = (const int*)d_in[1];
    const float* lw    = (const float*)d_in[2];
    const float* lb    = (const float*)d_in[3];
    const float* alpha = (const float*)d_in[4];
    const float* beta  = (const float*)d_in[5];
    const float* dxp   = (const float*)d_in[6];
    const float* dyp   = (const float*)d_in[7];
    const float* taup  = (const float*)d_in[8];
    const float* lnw   = (const float*)d_in[9];
    const float* lnb   = (const float*)d_in[10];
    const float* ow    = (const float*)d_in[11];
    const float* ob    = (const float*)d_in[12];
    const float* lsp   = (const float*)d_in[13];
    float* out = (float*)d_out;

    const int* srcp = ei;
    const int* dstp = ei + NE;

    char* ws = (char*)d_ws;
    size_t o = 0;
    auto alloc = [&](size_t b) { size_t r = o; o += (b + 255) & ~(size_t)255; return r; };
    int*            row_ptr = (int*)(ws + alloc((NN + 1) * sizeof(int)));
    int*            deg     = (int*)(ws + alloc(NN * sizeof(int)));
    int*            cnt     = (int*)(ws + alloc(NN * sizeof(int)));
    float*          dinv    = (float*)(ws + alloc(NN * sizeof(float)));
    int*            bsum    = (int*)(ws + alloc(256 * sizeof(int)));
    int*            boff    = (int*)(ws + alloc(256 * sizeof(int)));
    uint2*          edges   = (uint2*)(ws + alloc((size_t)NE * sizeof(uint2)));
    float*          hbuf    = (float*)(ws + alloc((size_t)NN * 128 * sizeof(float)));
    unsigned short* hbf8    = (unsigned short*)(ws + alloc((size_t)NN * HH * sizeof(unsigned short)));
    unsigned short* z1bf8   = (unsigned short*)(ws + alloc((size_t)NN * HH * sizeof(unsigned short)));

    hipMemsetAsync(deg, 0, NN * sizeof(int), stream);
    hipMemsetAsync(cnt, 0, NN * sizeof(int), stream);

    k_deg<<<(NE + 255) / 256, 256, 0, stream>>>(dstp, deg);
    k_scan1<<<NB_SCAN, 256, 0, stream>>>(deg, row_ptr, bsum, dinv);
    k_scan2<<<1, 256, 0, stream>>>(bsum, boff);
    k_scan3<<<NB_SCAN, 256, 0, stream>>>(row_ptr, boff);
    k_scatter<<<(NE + 255) / 256, 256, 0, stream>>>(srcp, dstp, dinv, row_ptr, cnt, edges);

    k_lift<<<NN / LIFT_NPB, 256, 0, stream>>>(x, lw, lb, hbuf, hbf8);

    for (int l = 0; l < NL; ++l) {
        k_spmm1<<<NN / 4, 256, 0, stream>>>(hbuf, hbf8, z1bf8, row_ptr, edges, alpha, beta, dxp, dyp, l);
        k_spmm2<<<NN / 4, 256, 0, stream>>>(hbuf, hbf8, z1bf8, row_ptr, edges, alpha, beta, dxp, dyp,
                                            taup, lnw, lnb, l);
    }

    k_out<<<(NN + 63) / 64, 256, 0, stream>>>(hbuf, ow, ob, lsp, out);
}